// Round 1
// baseline (1317.502 us; speedup 1.0000x reference)
//
#include <hip/hip_runtime.h>

#define N_NODES 50000
#define N_EDGES 800000
#define D_IN 128
#define D_HID 256
#define D_OUT 128

__global__ void deg_kernel(const int* __restrict__ dst, int* __restrict__ deg) {
    int i = blockIdx.x * blockDim.x + threadIdx.x;
    if (i < N_EDGES) atomicAdd(&deg[dst[i]], 1);
}

__global__ void deginv_kernel(const int* __restrict__ deg, float* __restrict__ deg_inv) {
    int i = blockIdx.x * blockDim.x + threadIdx.x;
    if (i < N_NODES) {
        float d = (float)deg[i];
        deg_inv[i] = 1.0f / fmaxf(d, 1.0f);
    }
}

// Scatter-add: agg[dst[e]][t] += feat[src[e]][t], element-per-thread grid-stride.
template<int F>
__global__ void scatter_kernel(const float* __restrict__ feat,
                               const int* __restrict__ src,
                               const int* __restrict__ dst,
                               float* __restrict__ agg) {
    constexpr int SH = (F == 128) ? 7 : 8;
    const int total = N_EDGES * F;           // fits in int32 (<= 204.8M)
    const int stride = gridDim.x * blockDim.x;
    for (int w = blockIdx.x * blockDim.x + threadIdx.x; w < total; w += stride) {
        int e = w >> SH;
        int t = w & (F - 1);
        int s = src[e];
        int d = dst[e];
        atomicAdd(&agg[d * F + t], feat[s * F + t]);
    }
}

// C[n][j] = opt_relu( sum_k rowscale[n]*Aa[n][k]*Ba[j][k] + sum_k Ab[n][k]*Bb[j][k] + bias[j] )
// Aa,Ab: [M x K] row-major. Ba,Bb: [J x K] row-major. C: [M x J].
// 64x64 tile, 256 threads, 4x4 per thread, K-chunk 16.
template<int K, int J, bool RELU>
__global__ __launch_bounds__(256)
void gemm_fused(const float* __restrict__ Aa, const float* __restrict__ Ba,
                const float* __restrict__ Ab, const float* __restrict__ Bb,
                const float* __restrict__ bias, const float* __restrict__ rowscale,
                float* __restrict__ C) {
    __shared__ float As[16][64];
    __shared__ float Bs[16][64];
    const int tid = threadIdx.x;
    const int tx = tid & 15;
    const int ty = tid >> 4;
    const int rowTile = blockIdx.y * 64;
    const int colTile = blockIdx.x * 64;
    const int lr = tid >> 2;          // 0..63: row within tile for loads
    const int lk = (tid & 3) * 4;     // 0,4,8,12: k offset for float4 load

    float acc[4][4] = {};

    for (int m = 0; m < 2; ++m) {
        const float* __restrict__ A = m ? Ab : Aa;
        const float* __restrict__ B = m ? Bb : Ba;
        for (int kc = 0; kc < K; kc += 16) {
            // A tile: rows may exceed M on the last row-tile
            int row = rowTile + lr;
            float4 av = make_float4(0.f, 0.f, 0.f, 0.f);
            if (row < N_NODES) {
                av = *(const float4*)&A[row * K + kc + lk];
                if (m == 0) {
                    float s = rowscale[row];
                    av.x *= s; av.y *= s; av.z *= s; av.w *= s;
                }
            }
            As[lk + 0][lr] = av.x;
            As[lk + 1][lr] = av.y;
            As[lk + 2][lr] = av.z;
            As[lk + 3][lr] = av.w;
            // B tile: J is a multiple of 64, always in bounds
            int col = colTile + lr;
            float4 bv = *(const float4*)&B[col * K + kc + lk];
            Bs[lk + 0][lr] = bv.x;
            Bs[lk + 1][lr] = bv.y;
            Bs[lk + 2][lr] = bv.z;
            Bs[lk + 3][lr] = bv.w;
            __syncthreads();
            #pragma unroll
            for (int k = 0; k < 16; ++k) {
                float4 af = *(const float4*)&As[k][ty * 4];
                float4 bf = *(const float4*)&Bs[k][tx * 4];
                float a[4] = {af.x, af.y, af.z, af.w};
                float b[4] = {bf.x, bf.y, bf.z, bf.w};
                #pragma unroll
                for (int i = 0; i < 4; ++i)
                    #pragma unroll
                    for (int j = 0; j < 4; ++j)
                        acc[i][j] += a[i] * b[j];
            }
            __syncthreads();
        }
    }

    // epilogue
    #pragma unroll
    for (int i = 0; i < 4; ++i) {
        int row = rowTile + ty * 4 + i;
        if (row < N_NODES) {
            int col = colTile + tx * 4;
            float4 o;
            o.x = acc[i][0] + bias[col + 0];
            o.y = acc[i][1] + bias[col + 1];
            o.z = acc[i][2] + bias[col + 2];
            o.w = acc[i][3] + bias[col + 3];
            if (RELU) {
                o.x = fmaxf(o.x, 0.f);
                o.y = fmaxf(o.y, 0.f);
                o.z = fmaxf(o.z, 0.f);
                o.w = fmaxf(o.w, 0.f);
            }
            *(float4*)&C[row * J + col] = o;
        }
    }
}

extern "C" void kernel_launch(void* const* d_in, const int* in_sizes, int n_in,
                              void* d_out, int out_size, void* d_ws, size_t ws_size,
                              hipStream_t stream) {
    const float* x   = (const float*)d_in[0];
    const float* Wl1 = (const float*)d_in[1];
    const float* bl1 = (const float*)d_in[2];
    const float* Wr1 = (const float*)d_in[3];
    const float* Wl2 = (const float*)d_in[4];
    const float* bl2 = (const float*)d_in[5];
    const float* Wr2 = (const float*)d_in[6];
    const int*   ei  = (const int*)d_in[7];
    const int* src = ei;              // edge_index[0]
    const int* dst = ei + N_EDGES;    // edge_index[1]
    float* out = (float*)d_out;

    // Workspace layout (floats):
    //   [0, 50000)                 deg_inv
    //   [50000, 100000)            deg (int)
    //   [100000, +6.4M)            agg1  [N, 128]
    //   [.., +12.8M)               agg2  [N, 256]
    //   [.., +12.8M)               h     [N, 256]
    float* f = (float*)d_ws;
    float* deg_inv = f;
    int*   deg     = (int*)(f + 50000);
    float* agg1    = f + 100000;
    float* agg2    = agg1 + (size_t)N_NODES * D_IN;
    float* h       = agg2 + (size_t)N_NODES * D_HID;

    // zero deg + agg1 + agg2 in one contiguous memset (ws is poisoned 0xAA each call)
    size_t zero_floats = (size_t)N_NODES + (size_t)N_NODES * D_IN + (size_t)N_NODES * D_HID;
    hipMemsetAsync(f + 50000, 0, zero_floats * sizeof(float), stream);

    deg_kernel<<<(N_EDGES + 255) / 256, 256, 0, stream>>>(dst, deg);
    deginv_kernel<<<(N_NODES + 255) / 256, 256, 0, stream>>>(deg, deg_inv);

    // Layer 1
    scatter_kernel<D_IN><<<4096, 256, 0, stream>>>(x, src, dst, agg1);
    gemm_fused<D_IN, D_HID, true>
        <<<dim3(D_HID / 64, (N_NODES + 63) / 64), 256, 0, stream>>>(
            agg1, Wl1, x, Wr1, bl1, deg_inv, h);

    // Layer 2
    scatter_kernel<D_HID><<<8192, 256, 0, stream>>>(h, src, dst, agg2);
    gemm_fused<D_HID, D_OUT, false>
        <<<dim3(D_OUT / 64, (N_NODES + 63) / 64), 256, 0, stream>>>(
            agg2, Wl2, h, Wr2, bl2, deg_inv, out);
}

// Round 3
// 593.625 us; speedup vs baseline: 2.2194x; 2.2194x over previous
//
#include <hip/hip_runtime.h>

#define N_NODES 50000
#define N_EDGES 800000
#define D_IN 128
#define D_HID 256
#define D_OUT 128

// ---------------- CSR build (no HIP memset APIs — kernels only) ----------------

__global__ void zero_deg(int* __restrict__ deg) {
    int i = blockIdx.x * blockDim.x + threadIdx.x;
    if (i < N_NODES) deg[i] = 0;
}

__global__ void deg_kernel(const int* __restrict__ dst, int* __restrict__ deg) {
    int i = blockIdx.x * blockDim.x + threadIdx.x;
    if (i < N_EDGES) atomicAdd(&deg[dst[i]], 1);
}

// Single-block exclusive scan of deg -> row_ptr (+cursor, +deg_inv).
// 1024 threads, Hillis-Steele per 1024-chunk with running carry.
__global__ __launch_bounds__(1024)
void build_rowptr(const int* __restrict__ deg, int* __restrict__ row_ptr,
                  int* __restrict__ cursor, float* __restrict__ deg_inv) {
    __shared__ int s[1024];
    __shared__ int carry_s;
    const int tid = threadIdx.x;
    if (tid == 0) carry_s = 0;
    __syncthreads();
    for (int base = 0; base < N_NODES; base += 1024) {
        int i = base + tid;
        int v = (i < N_NODES) ? deg[i] : 0;
        s[tid] = v;
        __syncthreads();
        #pragma unroll
        for (int off = 1; off < 1024; off <<= 1) {
            int t = (tid >= off) ? s[tid - off] : 0;
            __syncthreads();
            s[tid] += t;
            __syncthreads();
        }
        int carry = carry_s;
        if (i < N_NODES) {
            int rp = carry + s[tid] - v;   // exclusive prefix
            row_ptr[i] = rp;
            cursor[i] = rp;
            deg_inv[i] = 1.0f / fmaxf((float)v, 1.0f);
        }
        __syncthreads();                   // everyone has read carry_s
        if (tid == 0) carry_s += s[1023];
        __syncthreads();
    }
    if (tid == 0) row_ptr[N_NODES] = N_EDGES;
}

__global__ void fill_csr(const int* __restrict__ src, const int* __restrict__ dst,
                         int* __restrict__ cursor, int* __restrict__ csr_src) {
    int e = blockIdx.x * blockDim.x + threadIdx.x;
    if (e < N_EDGES) {
        int p = atomicAdd(&cursor[dst[e]], 1);
        csr_src[p] = src[e];
    }
}

// ---------------- mean aggregation (gather, owner-computes, no atomics) --------

template<int F, bool ACCUM>
__global__ __launch_bounds__(F)
void gather_mean(const float* __restrict__ feat, const int* __restrict__ row_ptr,
                 const int* __restrict__ csr_src, const float* __restrict__ deg_inv,
                 float* __restrict__ out) {
    const int n = blockIdx.x;
    const int t = threadIdx.x;
    const int beg = row_ptr[n];
    const int end = row_ptr[n + 1];
    float acc = 0.f;
    int e = beg;
    for (; e + 4 <= end; e += 4) {
        int s0 = csr_src[e + 0];
        int s1 = csr_src[e + 1];
        int s2 = csr_src[e + 2];
        int s3 = csr_src[e + 3];
        float v0 = feat[s0 * F + t];
        float v1 = feat[s1 * F + t];
        float v2 = feat[s2 * F + t];
        float v3 = feat[s3 * F + t];
        acc += (v0 + v1) + (v2 + v3);
    }
    for (; e < end; ++e) acc += feat[csr_src[e] * F + t];
    float r = acc * deg_inv[n];
    if (ACCUM) out[n * F + t] += r;   // out fully written by prior GEMM
    else       out[n * F + t] = r;
}

// ---------------- fused SGEMM ----------------
// C[n][j] = opt_relu( Aa[n,:]·Ba[j,:] (+ Ab[n,:]·Bb[j,:] if TWO) (+ bias[j] if BIAS) )
// 64x64 tile, 256 threads, 4x4 per thread, K-chunk 16.
template<int K, int J, bool TWO, bool RELU, bool BIAS>
__global__ __launch_bounds__(256)
void gemm_fused(const float* __restrict__ Aa, const float* __restrict__ Ba,
                const float* __restrict__ Ab, const float* __restrict__ Bb,
                const float* __restrict__ bias, float* __restrict__ C) {
    __shared__ float As[16][64];
    __shared__ float Bs[16][64];
    const int tid = threadIdx.x;
    const int tx = tid & 15;
    const int ty = tid >> 4;
    const int rowTile = blockIdx.y * 64;
    const int colTile = blockIdx.x * 64;
    const int lr = tid >> 2;          // 0..63: row within tile for loads
    const int lk = (tid & 3) * 4;     // 0,4,8,12: k offset for float4 load

    float acc[4][4] = {};

    #pragma unroll
    for (int m = 0; m < (TWO ? 2 : 1); ++m) {
        const float* __restrict__ A = (TWO && m) ? Ab : Aa;
        const float* __restrict__ B = (TWO && m) ? Bb : Ba;
        for (int kc = 0; kc < K; kc += 16) {
            int row = rowTile + lr;
            float4 av = make_float4(0.f, 0.f, 0.f, 0.f);
            if (row < N_NODES) av = *(const float4*)&A[row * K + kc + lk];
            As[lk + 0][lr] = av.x;
            As[lk + 1][lr] = av.y;
            As[lk + 2][lr] = av.z;
            As[lk + 3][lr] = av.w;
            int col = colTile + lr;   // J multiple of 64, in bounds
            float4 bv = *(const float4*)&B[col * K + kc + lk];
            Bs[lk + 0][lr] = bv.x;
            Bs[lk + 1][lr] = bv.y;
            Bs[lk + 2][lr] = bv.z;
            Bs[lk + 3][lr] = bv.w;
            __syncthreads();
            #pragma unroll
            for (int k = 0; k < 16; ++k) {
                float4 af = *(const float4*)&As[k][ty * 4];
                float4 bf = *(const float4*)&Bs[k][tx * 4];
                float a[4] = {af.x, af.y, af.z, af.w};
                float b[4] = {bf.x, bf.y, bf.z, bf.w};
                #pragma unroll
                for (int i = 0; i < 4; ++i)
                    #pragma unroll
                    for (int j = 0; j < 4; ++j)
                        acc[i][j] += a[i] * b[j];
            }
            __syncthreads();
        }
    }

    #pragma unroll
    for (int i = 0; i < 4; ++i) {
        int row = rowTile + ty * 4 + i;
        if (row < N_NODES) {
            int col = colTile + tx * 4;
            float4 o = make_float4(acc[i][0], acc[i][1], acc[i][2], acc[i][3]);
            if (BIAS) {
                o.x += bias[col + 0];
                o.y += bias[col + 1];
                o.z += bias[col + 2];
                o.w += bias[col + 3];
            }
            if (RELU) {
                o.x = fmaxf(o.x, 0.f);
                o.y = fmaxf(o.y, 0.f);
                o.z = fmaxf(o.z, 0.f);
                o.w = fmaxf(o.w, 0.f);
            }
            *(float4*)&C[row * J + col] = o;
        }
    }
}

extern "C" void kernel_launch(void* const* d_in, const int* in_sizes, int n_in,
                              void* d_out, int out_size, void* d_ws, size_t ws_size,
                              hipStream_t stream) {
    const float* x   = (const float*)d_in[0];
    const float* Wl1 = (const float*)d_in[1];
    const float* bl1 = (const float*)d_in[2];
    const float* Wr1 = (const float*)d_in[3];
    const float* Wl2 = (const float*)d_in[4];
    const float* bl2 = (const float*)d_in[5];
    const float* Wr2 = (const float*)d_in[6];
    const int*   ei  = (const int*)d_in[7];
    const int* src = ei;              // edge_index[0]
    const int* dst = ei + N_EDGES;    // edge_index[1]
    float* out = (float*)d_out;

    // Workspace layout (all offsets 16B-aligned where float4 access occurs).
    char* w = (char*)d_ws;
    int*   deg     = (int*)w;                       w += 50000 * 4;              // @0
    int*   row_ptr = (int*)w;                       w += 50004 * 4;
    int*   cursor  = (int*)w;                       w += 50000 * 4;
    int*   csr_src = (int*)w;                       w += (size_t)N_EDGES * 4;
    float* deg_inv = (float*)w;                     w += 50000 * 4;              // @3800016
    w += 16 - ((size_t)(w - (char*)d_ws) & 15);     // align pad (keeps 16B alignment)
    w = (char*)d_ws + (((size_t)(w - (char*)d_ws) + 15) & ~(size_t)15);
    float* mean1   = (float*)w;                     w += (size_t)N_NODES * D_IN * 4;
    float* h       = (float*)w;                     w += (size_t)N_NODES * D_HID * 4;
    float* p = mean1;   // p = h @ Wl2^T reuses mean1 (dead after layer-1 GEMM)

    // CSR build — kernels only, no HIP memory APIs inside the capture.
    zero_deg<<<(N_NODES + 255) / 256, 256, 0, stream>>>(deg);
    deg_kernel<<<(N_EDGES + 255) / 256, 256, 0, stream>>>(dst, deg);
    build_rowptr<<<1, 1024, 0, stream>>>(deg, row_ptr, cursor, deg_inv);
    fill_csr<<<(N_EDGES + 255) / 256, 256, 0, stream>>>(src, dst, cursor, csr_src);

    // Layer 1: h = relu(mean(x) @ Wl1^T + x @ Wr1^T + bl1)
    gather_mean<D_IN, false><<<N_NODES, D_IN, 0, stream>>>(x, row_ptr, csr_src, deg_inv, mean1);
    gemm_fused<D_IN, D_HID, true, true, true>
        <<<dim3(D_HID / 64, (N_NODES + 63) / 64), 256, 0, stream>>>(
            mean1, Wl1, x, Wr1, bl1, h);

    // Layer 2 (reordered, linearity of mean): p = h @ Wl2^T;
    // out = h @ Wr2^T + bl2; out += mean(p)
    gemm_fused<D_HID, D_OUT, false, false, false>
        <<<dim3(D_OUT / 64, (N_NODES + 63) / 64), 256, 0, stream>>>(
            h, Wl2, nullptr, nullptr, nullptr, p);
    gemm_fused<D_HID, D_OUT, false, false, true>
        <<<dim3(D_OUT / 64, (N_NODES + 63) / 64), 256, 0, stream>>>(
            h, Wr2, nullptr, nullptr, bl2, out);
    gather_mean<D_OUT, true><<<N_NODES, D_OUT, 0, stream>>>(p, row_ptr, csr_src, deg_inv, out);
}

// Round 4
// 436.058 us; speedup vs baseline: 3.0214x; 1.3613x over previous
//
#include <hip/hip_runtime.h>
#include <hip/hip_fp16.h>

#define N_NODES 50000
#define N_EDGES 800000
#define D_IN 128
#define D_HID 256
#define D_OUT 128
#define NCHUNK 196   // ceil(N_NODES / 256)

typedef _Float16 f16x8 __attribute__((ext_vector_type(8)));
typedef float f32x4 __attribute__((ext_vector_type(4)));

// ---------------- CSR build (kernels only; no HIP memory APIs in capture) -----

__global__ void zero_deg(int* __restrict__ deg) {
    int i = blockIdx.x * blockDim.x + threadIdx.x;
    if (i < N_NODES) deg[i] = 0;
}

__global__ void deg_kernel(const int* __restrict__ dst, int* __restrict__ deg) {
    int i = blockIdx.x * blockDim.x + threadIdx.x;
    if (i < N_EDGES) atomicAdd(&deg[dst[i]], 1);
}

__global__ void chunk_sum(const int* __restrict__ deg, int* __restrict__ partial) {
    __shared__ int s[256];
    int i = blockIdx.x * 256 + threadIdx.x;
    s[threadIdx.x] = (i < N_NODES) ? deg[i] : 0;
    __syncthreads();
    for (int off = 128; off > 0; off >>= 1) {
        if (threadIdx.x < off) s[threadIdx.x] += s[threadIdx.x + off];
        __syncthreads();
    }
    if (threadIdx.x == 0) partial[blockIdx.x] = s[0];
}

__global__ void chunk_scan(const int* __restrict__ partial, int* __restrict__ chunkOff) {
    __shared__ int s[256];
    int tid = threadIdx.x;
    int v = (tid < NCHUNK) ? partial[tid] : 0;
    s[tid] = v;
    __syncthreads();
    for (int off = 1; off < 256; off <<= 1) {
        int t = (tid >= off) ? s[tid - off] : 0;
        __syncthreads();
        s[tid] += t;
        __syncthreads();
    }
    if (tid < NCHUNK) chunkOff[tid] = s[tid] - v;   // exclusive
}

__global__ void scatter_scan(const int* __restrict__ deg, const int* __restrict__ chunkOff,
                             int* __restrict__ row_ptr, int* __restrict__ cursor,
                             float* __restrict__ deg_inv) {
    __shared__ int s[256];
    int tid = threadIdx.x;
    int i = blockIdx.x * 256 + tid;
    int v = (i < N_NODES) ? deg[i] : 0;
    s[tid] = v;
    __syncthreads();
    for (int off = 1; off < 256; off <<= 1) {
        int t = (tid >= off) ? s[tid - off] : 0;
        __syncthreads();
        s[tid] += t;
        __syncthreads();
    }
    if (i < N_NODES) {
        int rp = chunkOff[blockIdx.x] + s[tid] - v;   // exclusive scan value
        row_ptr[i] = rp;
        cursor[i] = rp;
        deg_inv[i] = 1.0f / fmaxf((float)v, 1.0f);
        if (i == N_NODES - 1) row_ptr[N_NODES] = N_EDGES;
    }
}

__global__ void fill_csr(const int* __restrict__ src, const int* __restrict__ dst,
                         int* __restrict__ cursor, int* __restrict__ csr_src) {
    int e = blockIdx.x * blockDim.x + threadIdx.x;
    if (e < N_EDGES) {
        int p = atomicAdd(&cursor[dst[e]], 1);
        csr_src[p] = src[e];
    }
}

// ---------------- fp32 -> fp16 conversion ----------------

__global__ void cvt_half(const float* __restrict__ in, __half2* __restrict__ out, int n2) {
    int i = blockIdx.x * blockDim.x + threadIdx.x;
    if (i < n2) {
        float2 v = ((const float2*)in)[i];
        out[i] = __float22half2_rn(v);
    }
}

// ---------------- mean aggregation (gather, wave-per-node, fp16 rows) ---------
// 128-feature rows = 64 half2; lane l handles cols 2l, 2l+1. fp32 accumulate.

__global__ __launch_bounds__(256)
void gather_mean_h(const __half2* __restrict__ feat, const int* __restrict__ row_ptr,
                   const int* __restrict__ csr_src, const float* __restrict__ deg_inv,
                   __half2* __restrict__ outv) {
    const int lane = threadIdx.x & 63;
    const int n = blockIdx.x * 4 + (threadIdx.x >> 6);   // grid exactly covers N_NODES
    const int beg = row_ptr[n];
    const int end = row_ptr[n + 1];
    float a0 = 0.f, a1 = 0.f;
    int e = beg;
    for (; e + 4 <= end; e += 4) {
        int s0 = csr_src[e + 0];
        int s1 = csr_src[e + 1];
        int s2 = csr_src[e + 2];
        int s3 = csr_src[e + 3];
        float2 v0 = __half22float2(feat[s0 * 64 + lane]);
        float2 v1 = __half22float2(feat[s1 * 64 + lane]);
        float2 v2 = __half22float2(feat[s2 * 64 + lane]);
        float2 v3 = __half22float2(feat[s3 * 64 + lane]);
        a0 += (v0.x + v1.x) + (v2.x + v3.x);
        a1 += (v0.y + v1.y) + (v2.y + v3.y);
    }
    for (; e < end; ++e) {
        float2 v = __half22float2(feat[csr_src[e] * 64 + lane]);
        a0 += v.x;
        a1 += v.y;
    }
    float di = deg_inv[n];
    outv[n * 64 + lane] = __float22half2_rn(make_float2(a0 * di, a1 * di));
}

// Same gather but accumulates mean into an existing fp32 output (out += mean(p)).
__global__ __launch_bounds__(256)
void gather_mean_add_f32(const __half2* __restrict__ feat, const int* __restrict__ row_ptr,
                         const int* __restrict__ csr_src, const float* __restrict__ deg_inv,
                         float* __restrict__ out) {
    const int lane = threadIdx.x & 63;
    const int n = blockIdx.x * 4 + (threadIdx.x >> 6);
    const int beg = row_ptr[n];
    const int end = row_ptr[n + 1];
    float a0 = 0.f, a1 = 0.f;
    int e = beg;
    for (; e + 4 <= end; e += 4) {
        int s0 = csr_src[e + 0];
        int s1 = csr_src[e + 1];
        int s2 = csr_src[e + 2];
        int s3 = csr_src[e + 3];
        float2 v0 = __half22float2(feat[s0 * 64 + lane]);
        float2 v1 = __half22float2(feat[s1 * 64 + lane]);
        float2 v2 = __half22float2(feat[s2 * 64 + lane]);
        float2 v3 = __half22float2(feat[s3 * 64 + lane]);
        a0 += (v0.x + v1.x) + (v2.x + v3.x);
        a1 += (v0.y + v1.y) + (v2.y + v3.y);
    }
    for (; e < end; ++e) {
        float2 v = __half22float2(feat[csr_src[e] * 64 + lane]);
        a0 += v.x;
        a1 += v.y;
    }
    float di = deg_inv[n];
    float2* o = (float2*)(out + (size_t)n * 128) + lane;
    float2 v = *o;
    v.x += a0 * di;
    v.y += a1 * di;
    *o = v;
}

// ---------------- MFMA fp16 GEMMs (no LDS; direct fragment loads) -------------
// mfma_f32_16x16x32_f16 layouts (guide-verified, dtype-independent C/D):
//   A frag: lane holds A[m0 + (lane&15)][kc + (lane>>4)*8 + j], j=0..7 (16B load)
//   B frag: lane holds W[n0 + (lane&15)][kc + (lane>>4)*8 + j]  (W is [J x K] row-major)
//   C/D:    col = n0 + (lane&15), row = m0 + (lane>>4)*4 + reg
// Block = 256 threads = 4 waves; wave w owns rows m0 = blockIdx.x*64 + w*16.

// Layer 1: H = relu(mean1 @ Wl1^T + x @ Wr1^T + bl1), H fp16 [N, 256]
__global__ __launch_bounds__(256)
void gemm_l1(const __half* __restrict__ Aa, const __half* __restrict__ Ba,
             const __half* __restrict__ Ab, const __half* __restrict__ Bb,
             const float* __restrict__ bias, __half* __restrict__ H) {
    const int lane = threadIdx.x & 63;
    const int m0 = blockIdx.x * 64 + (threadIdx.x >> 6) * 16;
    const int quad = lane >> 4;
    const int l16 = lane & 15;
    int mrow = m0 + l16;
    if (mrow > N_NODES - 1) mrow = N_NODES - 1;   // clamp; stores are guarded
    f32x4 acc[16] = {};
    #pragma unroll
    for (int pass = 0; pass < 2; ++pass) {
        const __half* __restrict__ A = pass ? Ab : Aa;
        const __half* __restrict__ B = pass ? Bb : Ba;
        #pragma unroll
        for (int kc = 0; kc < D_IN; kc += 32) {
            f16x8 af = *(const f16x8*)(A + (size_t)mrow * D_IN + kc + quad * 8);
            #pragma unroll
            for (int nt = 0; nt < 16; ++nt) {
                f16x8 bf = *(const f16x8*)(B + (size_t)(nt * 16 + l16) * D_IN + kc + quad * 8);
                acc[nt] = __builtin_amdgcn_mfma_f32_16x16x32_f16(af, bf, acc[nt], 0, 0, 0);
            }
        }
    }
    #pragma unroll
    for (int nt = 0; nt < 16; ++nt) {
        int col = nt * 16 + l16;
        float bv = bias[col];
        #pragma unroll
        for (int r = 0; r < 4; ++r) {
            int row = m0 + quad * 4 + r;
            if (row < N_NODES) {
                float v = fmaxf(acc[nt][r] + bv, 0.f);
                H[(size_t)row * D_HID + col] = __float2half(v);
            }
        }
    }
}

// Layer 2 fused: P = H @ Wl2^T (fp16, no bias); OUT = H @ Wr2^T + bl2 (fp32).
__global__ __launch_bounds__(256)
void gemm_l2(const __half* __restrict__ Hh, const __half* __restrict__ B0,
             const __half* __restrict__ B1, const float* __restrict__ bias,
             __half* __restrict__ P, float* __restrict__ out) {
    const int lane = threadIdx.x & 63;
    const int m0 = blockIdx.x * 64 + (threadIdx.x >> 6) * 16;
    const int quad = lane >> 4;
    const int l16 = lane & 15;
    int mrow = m0 + l16;
    if (mrow > N_NODES - 1) mrow = N_NODES - 1;
    f32x4 acc0[8] = {};
    f32x4 acc1[8] = {};
    #pragma unroll
    for (int kc = 0; kc < D_HID; kc += 32) {
        f16x8 af = *(const f16x8*)(Hh + (size_t)mrow * D_HID + kc + quad * 8);
        #pragma unroll
        for (int nt = 0; nt < 8; ++nt) {
            f16x8 b0 = *(const f16x8*)(B0 + (size_t)(nt * 16 + l16) * D_HID + kc + quad * 8);
            acc0[nt] = __builtin_amdgcn_mfma_f32_16x16x32_f16(af, b0, acc0[nt], 0, 0, 0);
            f16x8 b1 = *(const f16x8*)(B1 + (size_t)(nt * 16 + l16) * D_HID + kc + quad * 8);
            acc1[nt] = __builtin_amdgcn_mfma_f32_16x16x32_f16(af, b1, acc1[nt], 0, 0, 0);
        }
    }
    #pragma unroll
    for (int nt = 0; nt < 8; ++nt) {
        int col = nt * 16 + l16;
        float bv = bias[col];
        #pragma unroll
        for (int r = 0; r < 4; ++r) {
            int row = m0 + quad * 4 + r;
            if (row < N_NODES) {
                P[(size_t)row * D_OUT + col] = __float2half(acc0[nt][r]);
                out[(size_t)row * D_OUT + col] = acc1[nt][r] + bv;
            }
        }
    }
}

extern "C" void kernel_launch(void* const* d_in, const int* in_sizes, int n_in,
                              void* d_out, int out_size, void* d_ws, size_t ws_size,
                              hipStream_t stream) {
    const float* x   = (const float*)d_in[0];
    const float* Wl1 = (const float*)d_in[1];
    const float* bl1 = (const float*)d_in[2];
    const float* Wr1 = (const float*)d_in[3];
    const float* Wl2 = (const float*)d_in[4];
    const float* bl2 = (const float*)d_in[5];
    const float* Wr2 = (const float*)d_in[6];
    const int*   ei  = (const int*)d_in[7];
    const int* src = ei;              // edge_index[0]
    const int* dst = ei + N_EDGES;    // edge_index[1]
    float* out = (float*)d_out;

    // Workspace layout, 256B-aligned slabs (~68 MB total)
    char* w = (char*)d_ws;
    auto alloc = [&](size_t bytes) {
        char* r = w;
        w += (bytes + 255) & ~(size_t)255;
        return r;
    };
    int*     deg      = (int*)alloc((size_t)N_NODES * 4);
    int*     row_ptr  = (int*)alloc((size_t)(N_NODES + 1) * 4);
    int*     cursor   = (int*)alloc((size_t)N_NODES * 4);
    int*     partial  = (int*)alloc(NCHUNK * 4);
    int*     chunkOff = (int*)alloc(NCHUNK * 4);
    int*     csr_src  = (int*)alloc((size_t)N_EDGES * 4);
    float*   deg_inv  = (float*)alloc((size_t)N_NODES * 4);
    __half2* xb       = (__half2*)alloc((size_t)N_NODES * 64 * 4);   // x fp16 [N,128]
    __half2* mean1    = (__half2*)alloc((size_t)N_NODES * 64 * 4);   // mean(x) fp16
    __half*  h        = (__half*)alloc((size_t)N_NODES * 256 * 2);   // layer-1 out fp16
    __half2* pb       = (__half2*)alloc((size_t)N_NODES * 64 * 4);   // h@Wl2^T fp16
    __half*  wl1h     = (__half*)alloc(4 * 32768 * 2);               // 4 weight mats fp16
    __half*  wr1h = wl1h + 32768;
    __half*  wl2h = wr1h + 32768;
    __half*  wr2h = wl2h + 32768;

    // CSR build
    zero_deg<<<(N_NODES + 255) / 256, 256, 0, stream>>>(deg);
    deg_kernel<<<(N_EDGES + 255) / 256, 256, 0, stream>>>(dst, deg);
    chunk_sum<<<NCHUNK, 256, 0, stream>>>(deg, partial);
    chunk_scan<<<1, 256, 0, stream>>>(partial, chunkOff);
    scatter_scan<<<NCHUNK, 256, 0, stream>>>(deg, chunkOff, row_ptr, cursor, deg_inv);
    fill_csr<<<(N_EDGES + 255) / 256, 256, 0, stream>>>(src, dst, cursor, csr_src);

    // fp16 conversions (independent of CSR; stream-ordered)
    cvt_half<<<12500, 256, 0, stream>>>(x, xb, N_NODES * 64);
    cvt_half<<<64, 256, 0, stream>>>(Wl1, (__half2*)wl1h, 16384);
    cvt_half<<<64, 256, 0, stream>>>(Wr1, (__half2*)wr1h, 16384);
    cvt_half<<<64, 256, 0, stream>>>(Wl2, (__half2*)wl2h, 16384);
    cvt_half<<<64, 256, 0, stream>>>(Wr2, (__half2*)wr2h, 16384);

    // Layer 1: h = relu(mean(x) @ Wl1^T + x @ Wr1^T + bl1)
    gather_mean_h<<<12500, 256, 0, stream>>>(xb, row_ptr, csr_src, deg_inv, mean1);
    gemm_l1<<<(N_NODES + 63) / 64, 256, 0, stream>>>(
        (const __half*)mean1, wl1h, (const __half*)xb, wr1h, bl1, h);

    // Layer 2 (reordered): p = h @ Wl2^T; out = h @ Wr2^T + bl2; out += mean(p)
    gemm_l2<<<(N_NODES + 63) / 64, 256, 0, stream>>>(
        h, wl2h, wr2h, bl2, (__half*)pb, out);
    gather_mean_add_f32<<<12500, 256, 0, stream>>>(pb, row_ptr, csr_src, deg_inv, out);
}

// Round 5
// 312.017 us; speedup vs baseline: 4.2225x; 1.3975x over previous
//
#include <hip/hip_runtime.h>
#include <hip/hip_fp16.h>

#define N_NODES 50000
#define N_EDGES 800000
#define D_IN 128
#define D_HID 256
#define D_OUT 128
#define NCHUNK 196   // ceil(N_NODES / 256)
#define GEMM_GRID 512

typedef _Float16 f16x8 __attribute__((ext_vector_type(8)));
typedef float f32x4 __attribute__((ext_vector_type(4)));

// ---------------- CSR build (kernels only; no HIP memory APIs in capture) -----

__global__ void zero_deg(int* __restrict__ deg) {
    int i = blockIdx.x * blockDim.x + threadIdx.x;
    if (i < N_NODES) deg[i] = 0;
}

__global__ void deg_kernel(const int* __restrict__ dst, int* __restrict__ deg) {
    int i = blockIdx.x * blockDim.x + threadIdx.x;
    if (i < N_EDGES) atomicAdd(&deg[dst[i]], 1);
}

__global__ void chunk_sum(const int* __restrict__ deg, int* __restrict__ partial) {
    __shared__ int s[256];
    int i = blockIdx.x * 256 + threadIdx.x;
    s[threadIdx.x] = (i < N_NODES) ? deg[i] : 0;
    __syncthreads();
    for (int off = 128; off > 0; off >>= 1) {
        if (threadIdx.x < off) s[threadIdx.x] += s[threadIdx.x + off];
        __syncthreads();
    }
    if (threadIdx.x == 0) partial[blockIdx.x] = s[0];
}

__global__ void chunk_scan(const int* __restrict__ partial, int* __restrict__ chunkOff) {
    __shared__ int s[256];
    int tid = threadIdx.x;
    int v = (tid < NCHUNK) ? partial[tid] : 0;
    s[tid] = v;
    __syncthreads();
    for (int off = 1; off < 256; off <<= 1) {
        int t = (tid >= off) ? s[tid - off] : 0;
        __syncthreads();
        s[tid] += t;
        __syncthreads();
    }
    if (tid < NCHUNK) chunkOff[tid] = s[tid] - v;   // exclusive
}

__global__ void scatter_scan(const int* __restrict__ deg, const int* __restrict__ chunkOff,
                             int* __restrict__ row_ptr, int* __restrict__ cursor,
                             float* __restrict__ deg_inv) {
    __shared__ int s[256];
    int tid = threadIdx.x;
    int i = blockIdx.x * 256 + tid;
    int v = (i < N_NODES) ? deg[i] : 0;
    s[tid] = v;
    __syncthreads();
    for (int off = 1; off < 256; off <<= 1) {
        int t = (tid >= off) ? s[tid - off] : 0;
        __syncthreads();
        s[tid] += t;
        __syncthreads();
    }
    if (i < N_NODES) {
        int rp = chunkOff[blockIdx.x] + s[tid] - v;   // exclusive scan value
        row_ptr[i] = rp;
        cursor[i] = rp;
        deg_inv[i] = 1.0f / fmaxf((float)v, 1.0f);
        if (i == N_NODES - 1) row_ptr[N_NODES] = N_EDGES;
    }
}

__global__ void fill_csr(const int* __restrict__ src, const int* __restrict__ dst,
                         int* __restrict__ cursor, int* __restrict__ csr_src) {
    int e = blockIdx.x * blockDim.x + threadIdx.x;
    if (e < N_EDGES) {
        int p = atomicAdd(&cursor[dst[e]], 1);
        csr_src[p] = src[e];
    }
}

// ---------------- fp32 -> fp16 conversion ----------------

__global__ void cvt_half(const float* __restrict__ in, __half2* __restrict__ out, int n2) {
    int i = blockIdx.x * blockDim.x + threadIdx.x;
    if (i < n2) {
        float2 v = ((const float2*)in)[i];
        out[i] = __float22half2_rn(v);
    }
}

// ---------------- mean aggregation (gather, wave-per-node, fp16 rows) ---------

__global__ __launch_bounds__(256)
void gather_mean_h(const __half2* __restrict__ feat, const int* __restrict__ row_ptr,
                   const int* __restrict__ csr_src, const float* __restrict__ deg_inv,
                   __half2* __restrict__ outv) {
    const int lane = threadIdx.x & 63;
    const int n = blockIdx.x * 4 + (threadIdx.x >> 6);   // grid exactly covers N_NODES
    const int beg = row_ptr[n];
    const int end = row_ptr[n + 1];
    float a0 = 0.f, a1 = 0.f;
    int e = beg;
    for (; e + 4 <= end; e += 4) {
        int s0 = csr_src[e + 0];
        int s1 = csr_src[e + 1];
        int s2 = csr_src[e + 2];
        int s3 = csr_src[e + 3];
        float2 v0 = __half22float2(feat[s0 * 64 + lane]);
        float2 v1 = __half22float2(feat[s1 * 64 + lane]);
        float2 v2 = __half22float2(feat[s2 * 64 + lane]);
        float2 v3 = __half22float2(feat[s3 * 64 + lane]);
        a0 += (v0.x + v1.x) + (v2.x + v3.x);
        a1 += (v0.y + v1.y) + (v2.y + v3.y);
    }
    for (; e < end; ++e) {
        float2 v = __half22float2(feat[csr_src[e] * 64 + lane]);
        a0 += v.x;
        a1 += v.y;
    }
    float di = deg_inv[n];
    outv[n * 64 + lane] = __float22half2_rn(make_float2(a0 * di, a1 * di));
}

__global__ __launch_bounds__(256)
void gather_mean_add_f32(const __half2* __restrict__ feat, const int* __restrict__ row_ptr,
                         const int* __restrict__ csr_src, const float* __restrict__ deg_inv,
                         float* __restrict__ out) {
    const int lane = threadIdx.x & 63;
    const int n = blockIdx.x * 4 + (threadIdx.x >> 6);
    const int beg = row_ptr[n];
    const int end = row_ptr[n + 1];
    float a0 = 0.f, a1 = 0.f;
    int e = beg;
    for (; e + 4 <= end; e += 4) {
        int s0 = csr_src[e + 0];
        int s1 = csr_src[e + 1];
        int s2 = csr_src[e + 2];
        int s3 = csr_src[e + 3];
        float2 v0 = __half22float2(feat[s0 * 64 + lane]);
        float2 v1 = __half22float2(feat[s1 * 64 + lane]);
        float2 v2 = __half22float2(feat[s2 * 64 + lane]);
        float2 v3 = __half22float2(feat[s3 * 64 + lane]);
        a0 += (v0.x + v1.x) + (v2.x + v3.x);
        a1 += (v0.y + v1.y) + (v2.y + v3.y);
    }
    for (; e < end; ++e) {
        float2 v = __half22float2(feat[csr_src[e] * 64 + lane]);
        a0 += v.x;
        a1 += v.y;
    }
    float di = deg_inv[n];
    float2* o = (float2*)(out + (size_t)n * 128) + lane;
    float2 v = *o;
    v.x += a0 * di;
    v.y += a1 * di;
    *o = v;
}

// ---------------- MFMA fp16 GEMMs: B hoisted to registers, row-tile loop ------
// mfma_f32_16x16x32_f16 layouts (verified by R4 passing):
//   A frag: lane holds A[m = lane&15][k = kc + (lane>>4)*8 + j]
//   B frag: lane holds W[n = lane&15][k = kc + (lane>>4)*8 + j]  (W row-major [J,K])
//   C/D:    col = lane&15 (n), row = (lane>>4)*4 + reg
// Block = 4 waves; wave owns a column slice, preloads ALL its B frags (128 VGPRs),
// then grid-strides over 16-row tiles (N_NODES/16 = 3125 exactly; no tail).

// Layer 1: H = relu(mean1 @ Wl1^T + x @ Wr1^T + bl1), H fp16 [N, 256]
__global__ __launch_bounds__(256, 2)
void gemm_l1(const __half* __restrict__ Aa, const __half* __restrict__ Ba,
             const __half* __restrict__ Ab, const __half* __restrict__ Bb,
             const float* __restrict__ bias, __half* __restrict__ H) {
    const int lane = threadIdx.x & 63;
    const int wave = threadIdx.x >> 6;      // owns cols [wave*64, wave*64+64)
    const int quad = lane >> 4;
    const int l16 = lane & 15;
    const int koff = quad * 8;

    // Hoist B fragments: bf[pass][kc][nt]  (32 x f16x8 = 128 VGPRs)
    f16x8 bf[2][4][4];
    #pragma unroll
    for (int p = 0; p < 2; ++p) {
        const __half* __restrict__ B = p ? Bb : Ba;
        #pragma unroll
        for (int kc = 0; kc < 4; ++kc)
            #pragma unroll
            for (int nt = 0; nt < 4; ++nt)
                bf[p][kc][nt] = *(const f16x8*)(
                    B + (size_t)(wave * 64 + nt * 16 + l16) * D_IN + kc * 32 + koff);
    }
    float bv[4];
    #pragma unroll
    for (int nt = 0; nt < 4; ++nt) bv[nt] = bias[wave * 64 + nt * 16 + l16];

    const int NT = N_NODES / 16;            // 3125
    const int g = gridDim.x;

    auto loadA = [&](int t, f16x8 (&a)[2][4]) {
        const size_t arow = (size_t)(t * 16 + l16) * D_IN + koff;
        #pragma unroll
        for (int kc = 0; kc < 4; ++kc) {
            a[0][kc] = *(const f16x8*)(Aa + arow + kc * 32);
            a[1][kc] = *(const f16x8*)(Ab + arow + kc * 32);
        }
    };
    auto step = [&](int tile, const f16x8 (&a)[2][4]) {
        f32x4 acc[4] = {};
        #pragma unroll
        for (int p = 0; p < 2; ++p)
            #pragma unroll
            for (int kc = 0; kc < 4; ++kc)
                #pragma unroll
                for (int nt = 0; nt < 4; ++nt)
                    acc[nt] = __builtin_amdgcn_mfma_f32_16x16x32_f16(
                        a[p][kc], bf[p][kc][nt], acc[nt], 0, 0, 0);
        #pragma unroll
        for (int nt = 0; nt < 4; ++nt) {
            int col = wave * 64 + nt * 16 + l16;
            #pragma unroll
            for (int r = 0; r < 4; ++r) {
                int row = tile * 16 + quad * 4 + r;
                H[(size_t)row * D_HID + col] =
                    __float2half(fmaxf(acc[nt][r] + bv[nt], 0.f));
            }
        }
    };

    f16x8 A0[2][4], A1[2][4];
    int tile = blockIdx.x;
    loadA(tile, A0);
    while (true) {
        if (tile + g < NT) loadA(tile + g, A1);
        step(tile, A0);
        tile += g;
        if (tile >= NT) break;
        if (tile + g < NT) loadA(tile + g, A0);
        step(tile, A1);
        tile += g;
        if (tile >= NT) break;
    }
}

// Layer 2 fused: P = H @ Wl2^T (fp16); OUT = H @ Wr2^T + bl2 (fp32). K = 256.
__global__ __launch_bounds__(256, 2)
void gemm_l2(const __half* __restrict__ Hh, const __half* __restrict__ B0,
             const __half* __restrict__ B1, const float* __restrict__ bias,
             __half* __restrict__ P, float* __restrict__ out) {
    const int lane = threadIdx.x & 63;
    const int wave = threadIdx.x >> 6;      // owns cols [wave*32, wave*32+32) of P and OUT
    const int quad = lane >> 4;
    const int l16 = lane & 15;
    const int koff = quad * 8;

    // Hoist B fragments: bf0/bf1[kc][nt]  (32 x f16x8 = 128 VGPRs)
    f16x8 bf0[8][2], bf1[8][2];
    #pragma unroll
    for (int kc = 0; kc < 8; ++kc)
        #pragma unroll
        for (int nt = 0; nt < 2; ++nt) {
            size_t brow = (size_t)(wave * 32 + nt * 16 + l16) * D_HID + kc * 32 + koff;
            bf0[kc][nt] = *(const f16x8*)(B0 + brow);
            bf1[kc][nt] = *(const f16x8*)(B1 + brow);
        }
    float bv[2];
    #pragma unroll
    for (int nt = 0; nt < 2; ++nt) bv[nt] = bias[wave * 32 + nt * 16 + l16];

    const int NT = N_NODES / 16;            // 3125
    const int g = gridDim.x;

    auto loadA = [&](int t, f16x8 (&a)[8]) {
        const size_t arow = (size_t)(t * 16 + l16) * D_HID + koff;
        #pragma unroll
        for (int kc = 0; kc < 8; ++kc)
            a[kc] = *(const f16x8*)(Hh + arow + kc * 32);
    };
    auto step = [&](int tile, const f16x8 (&a)[8]) {
        f32x4 acc0[2] = {};
        f32x4 acc1[2] = {};
        #pragma unroll
        for (int kc = 0; kc < 8; ++kc)
            #pragma unroll
            for (int nt = 0; nt < 2; ++nt) {
                acc0[nt] = __builtin_amdgcn_mfma_f32_16x16x32_f16(
                    a[kc], bf0[kc][nt], acc0[nt], 0, 0, 0);
                acc1[nt] = __builtin_amdgcn_mfma_f32_16x16x32_f16(
                    a[kc], bf1[kc][nt], acc1[nt], 0, 0, 0);
            }
        #pragma unroll
        for (int nt = 0; nt < 2; ++nt) {
            int col = wave * 32 + nt * 16 + l16;
            #pragma unroll
            for (int r = 0; r < 4; ++r) {
                int row = tile * 16 + quad * 4 + r;
                P[(size_t)row * D_OUT + col] = __float2half(acc0[nt][r]);
                out[(size_t)row * D_OUT + col] = acc1[nt][r] + bv[nt];
            }
        }
    };

    f16x8 A0[8], A1[8];
    int tile = blockIdx.x;
    loadA(tile, A0);
    while (true) {
        if (tile + g < NT) loadA(tile + g, A1);
        step(tile, A0);
        tile += g;
        if (tile >= NT) break;
        if (tile + g < NT) loadA(tile + g, A0);
        step(tile, A1);
        tile += g;
        if (tile >= NT) break;
    }
}

extern "C" void kernel_launch(void* const* d_in, const int* in_sizes, int n_in,
                              void* d_out, int out_size, void* d_ws, size_t ws_size,
                              hipStream_t stream) {
    const float* x   = (const float*)d_in[0];
    const float* Wl1 = (const float*)d_in[1];
    const float* bl1 = (const float*)d_in[2];
    const float* Wr1 = (const float*)d_in[3];
    const float* Wl2 = (const float*)d_in[4];
    const float* bl2 = (const float*)d_in[5];
    const float* Wr2 = (const float*)d_in[6];
    const int*   ei  = (const int*)d_in[7];
    const int* src = ei;              // edge_index[0]
    const int* dst = ei + N_EDGES;    // edge_index[1]
    float* out = (float*)d_out;

    // Workspace layout, 256B-aligned slabs (~68 MB total)
    char* w = (char*)d_ws;
    auto alloc = [&](size_t bytes) {
        char* r = w;
        w += (bytes + 255) & ~(size_t)255;
        return r;
    };
    int*     deg      = (int*)alloc((size_t)N_NODES * 4);
    int*     row_ptr  = (int*)alloc((size_t)(N_NODES + 1) * 4);
    int*     cursor   = (int*)alloc((size_t)N_NODES * 4);
    int*     partial  = (int*)alloc(NCHUNK * 4);
    int*     chunkOff = (int*)alloc(NCHUNK * 4);
    int*     csr_src  = (int*)alloc((size_t)N_EDGES * 4);
    float*   deg_inv  = (float*)alloc((size_t)N_NODES * 4);
    __half2* xb       = (__half2*)alloc((size_t)N_NODES * 64 * 4);   // x fp16 [N,128]
    __half2* mean1    = (__half2*)alloc((size_t)N_NODES * 64 * 4);   // mean(x) fp16
    __half*  h        = (__half*)alloc((size_t)N_NODES * 256 * 2);   // layer-1 out fp16
    __half2* pb       = (__half2*)alloc((size_t)N_NODES * 64 * 4);   // h@Wl2^T fp16
    __half*  wl1h     = (__half*)alloc(4 * 32768 * 2);               // 4 weight mats fp16
    __half*  wr1h = wl1h + 32768;
    __half*  wl2h = wr1h + 32768;
    __half*  wr2h = wl2h + 32768;

    // CSR build
    zero_deg<<<(N_NODES + 255) / 256, 256, 0, stream>>>(deg);
    deg_kernel<<<(N_EDGES + 255) / 256, 256, 0, stream>>>(dst, deg);
    chunk_sum<<<NCHUNK, 256, 0, stream>>>(deg, partial);
    chunk_scan<<<1, 256, 0, stream>>>(partial, chunkOff);
    scatter_scan<<<NCHUNK, 256, 0, stream>>>(deg, chunkOff, row_ptr, cursor, deg_inv);
    fill_csr<<<(N_EDGES + 255) / 256, 256, 0, stream>>>(src, dst, cursor, csr_src);

    // fp16 conversions
    cvt_half<<<12500, 256, 0, stream>>>(x, xb, N_NODES * 64);
    cvt_half<<<64, 256, 0, stream>>>(Wl1, (__half2*)wl1h, 16384);
    cvt_half<<<64, 256, 0, stream>>>(Wr1, (__half2*)wr1h, 16384);
    cvt_half<<<64, 256, 0, stream>>>(Wl2, (__half2*)wl2h, 16384);
    cvt_half<<<64, 256, 0, stream>>>(Wr2, (__half2*)wr2h, 16384);

    // Layer 1: h = relu(mean(x) @ Wl1^T + x @ Wr1^T + bl1)
    gather_mean_h<<<12500, 256, 0, stream>>>(xb, row_ptr, csr_src, deg_inv, mean1);
    gemm_l1<<<GEMM_GRID, 256, 0, stream>>>(
        (const __half*)mean1, wl1h, (const __half*)xb, wr1h, bl1, h);

    // Layer 2 (reordered): p = h @ Wl2^T; out = h @ Wr2^T + bl2; out += mean(p)
    gemm_l2<<<GEMM_GRID, 256, 0, stream>>>(
        h, wl2h, wr2h, bl2, (__half*)pb, out);
    gather_mean_add_f32<<<12500, 256, 0, stream>>>(pb, row_ptr, csr_src, deg_inv, out);
}